// Round 3
// baseline (430.810 us; speedup 1.0000x reference)
//
#include <hip/hip_runtime.h>
#include <hip/hip_bf16.h>

#define M_IN  32768
#define K_EMB 4096
#define D_DIM 256

#define BM 256
#define BN 256
#define BK 32     // K-tile depth: [256][32] bf16 = 64B row stride -> bank-conflict-free frag reads

// ---- ws layout (bytes) ----
#define WS_HWSQ   0         // float[4096]
#define WS_PACKS  16384     // u64[32768]
#define WS_COUNTS 278528    // int[4096]
#define WS_LOSS   294912    // float[64]
#define WS_XSQ    295168    // float[32768]

using f32x4  = __attribute__((ext_vector_type(4))) float;
using bf16x8 = __attribute__((ext_vector_type(8))) short;

#define GLL16(g, p) __builtin_amdgcn_global_load_lds( \
    (const __attribute__((address_space(1))) void*)(g), \
    (__attribute__((address_space(3))) void*)(p), 16, 0, 0)

__device__ __forceinline__ unsigned short bf16_rtn(float f) {
    __hip_bfloat16 h = __float2bfloat16(f);
    return *reinterpret_cast<unsigned short*>(&h);
}

// ---------------- convx: X -> bf16, xsq per row, packs init ----------------
__global__ __launch_bounds__(256) void convx_kernel(const float* __restrict__ X,
                                                    unsigned short* __restrict__ Xb,
                                                    float* __restrict__ xsq,
                                                    unsigned long long* __restrict__ packs)
{
    const int l  = threadIdx.x & 63;
    const int wv = threadIdx.x >> 6;
    const int n  = blockIdx.x * 4 + wv;
    float4 v = ((const float4*)(X + (size_t)n * D_DIM))[l];
    float s = v.x * v.x + v.y * v.y + v.z * v.z + v.w * v.w;
    union { unsigned short u[4]; uint2 q; } p;
    p.u[0] = bf16_rtn(v.x); p.u[1] = bf16_rtn(v.y);
    p.u[2] = bf16_rtn(v.z); p.u[3] = bf16_rtn(v.w);
    ((uint2*)(Xb + (size_t)n * D_DIM))[l] = p.q;
#pragma unroll
    for (int off = 32; off; off >>= 1) s += __shfl_xor(s, off);
    if (l == 0) { xsq[n] = s; packs[n] = ~0ull; }
}

// ---------------- convw: W -> bf16 + 0.5||w||^2 + zero counts/loss ----------------
__global__ __launch_bounds__(256) void convw_kernel(const float* __restrict__ W,
                                                    unsigned short* __restrict__ Wb,
                                                    float* __restrict__ hwsq,
                                                    int* __restrict__ counts,
                                                    float* __restrict__ loss_slots)
{
    const int l = threadIdx.x & 63;
    const int k = blockIdx.x * 4 + (threadIdx.x >> 6);
    const int g = blockIdx.x * 256 + threadIdx.x;
    if (g < K_EMB) counts[g] = 0;
    if (g < 64)    loss_slots[g] = 0.f;
    float4 v = ((const float4*)(W + (size_t)k * D_DIM))[l];
    float s = v.x * v.x + v.y * v.y + v.z * v.z + v.w * v.w;
    union { unsigned short u[4]; uint2 q; } p;
    p.u[0] = bf16_rtn(v.x); p.u[1] = bf16_rtn(v.y);
    p.u[2] = bf16_rtn(v.z); p.u[3] = bf16_rtn(v.w);
    ((uint2*)(Wb + (size_t)k * D_DIM))[l] = p.q;
#pragma unroll
    for (int off = 32; off; off >>= 1) s += __shfl_xor(s, off);
    if (l == 0) hwsq[k] = 0.5f * s;
}

// ---------------- dist: 256x256 tile, BK=32, 4-slot counted-vmcnt pipeline ----------------
// 8 waves (2M x 4N), per-wave 128x64 output, 8 K-tiles. Slots: kt%4. Stage-ahead-3.
// Safety: STAGE(T+3) (overwrites slot (T-1)%4) issues only after iter-T barrier; every
// wave drained its iter-(T-1) ds_reads (lgkmcnt(0)) before reaching that barrier.

#define STAGE_A(KT, S) { \
  _Pragma("unroll") \
  for (int j_ = 0; j_ < 2; ++j_) { \
    const int row_ = (j_*8 + w)*16 + (l >> 2); \
    const unsigned short* src_ = Xb + (size_t)(m0 + row_) * D_DIM + (KT)*BK + (l & 3)*8; \
    GLL16(src_, lds + (S)*32768 + (j_*8 + w)*1024); \
  } }

#define STAGE_B(KT, S) { \
  _Pragma("unroll") \
  for (int j_ = 0; j_ < 2; ++j_) { \
    const int row_ = (j_*8 + w)*16 + (l >> 2); \
    const unsigned short* src_ = Wb + (size_t)(nbase + row_) * D_DIM + (KT)*BK + (l & 3)*8; \
    GLL16(src_, lds + (S)*32768 + 16384 + (j_*8 + w)*1024); \
  } }

#define K_ITER(T, VM)                                                          \
  {                                                                            \
    asm volatile("s_waitcnt vmcnt(" #VM ")" ::: "memory");                     \
    __builtin_amdgcn_s_barrier();                                              \
    __builtin_amdgcn_sched_barrier(0);                                         \
    const char* As_ = (const char*)lds + ((T)&3)*32768;                        \
    const char* Bs_ = As_ + 16384;                                             \
    if ((T) < 5) STAGE_A((T)+3, ((T)+3)&3);                                    \
    bf16x8 bfr[4], af[4];                                                      \
    _Pragma("unroll")                                                          \
    for (int nj = 0; nj < 4; nj++)                                             \
      bfr[nj] = *(const bf16x8*)(Bs_ + (rbB + nj*16)*64 + cA);                 \
    _Pragma("unroll")                                                          \
    for (int mi = 0; mi < 4; mi++)                                             \
      af[mi] = *(const bf16x8*)(As_ + (rbA + mi*16)*64 + cA);                  \
    asm volatile("s_waitcnt lgkmcnt(0)" ::: "memory");                         \
    __builtin_amdgcn_sched_barrier(0);                                         \
    __builtin_amdgcn_s_setprio(1);                                             \
    _Pragma("unroll")                                                          \
    for (int mi = 0; mi < 4; mi++)                                             \
      _Pragma("unroll")                                                        \
      for (int nj = 0; nj < 4; nj++)                                           \
        acc[mi][nj] = __builtin_amdgcn_mfma_f32_16x16x32_bf16(                 \
            af[mi], bfr[nj], acc[mi][nj], 0, 0, 0);                            \
    __builtin_amdgcn_s_setprio(0);                                             \
    if ((T) < 5) STAGE_B((T)+3, ((T)+3)&3);                                    \
    _Pragma("unroll")                                                          \
    for (int mi = 0; mi < 4; mi++)                                             \
      af[mi] = *(const bf16x8*)(As_ + (rbA + 64 + mi*16)*64 + cA);             \
    asm volatile("s_waitcnt lgkmcnt(0)" ::: "memory");                         \
    __builtin_amdgcn_sched_barrier(0);                                         \
    __builtin_amdgcn_s_setprio(1);                                             \
    _Pragma("unroll")                                                          \
    for (int mi = 0; mi < 4; mi++)                                             \
      _Pragma("unroll")                                                        \
      for (int nj = 0; nj < 4; nj++)                                           \
        acc[4+mi][nj] = __builtin_amdgcn_mfma_f32_16x16x32_bf16(               \
            af[mi], bfr[nj], acc[4+mi][nj], 0, 0, 0);                          \
    __builtin_amdgcn_s_setprio(0);                                             \
  }

__global__ __launch_bounds__(512, 2) void dist_kernel(const unsigned short* __restrict__ Xb,
                                                      const unsigned short* __restrict__ Wb,
                                                      const float* __restrict__ hwsq,
                                                      unsigned long long* __restrict__ packs)
{
    __shared__ char lds[131072];   // 4 slots x (A 16KB + B 16KB)

    const int t = threadIdx.x;
    const int l = t & 63;
    const int w = t >> 6;
    const int wm = w >> 2, wn = w & 3;

    // XCD-bijective swizzle: 2048 blocks, 2048 % 8 == 0
    const int id  = blockIdx.x;
    const int swz = (id & 7) * 256 + (id >> 3);
    const int nb = swz & 15, mb = swz >> 4;
    const int m0 = mb * BM, nbase = nb * BN;

    const int rbA = wm * 128 + (l & 15);
    const int rbB = wn * 64  + (l & 15);
    const int cA  = (l >> 4) * 16;   // byte offset: lane's 8-bf16 K-chunk

    f32x4 acc[8][4];
#pragma unroll
    for (int mi = 0; mi < 8; mi++)
#pragma unroll
        for (int nj = 0; nj < 4; nj++) acc[mi][nj] = (f32x4){0.f, 0.f, 0.f, 0.f};

    // prologue: stage T0,T1,T2 (12 loads/thread outstanding)
    STAGE_A(0, 0); STAGE_B(0, 0);
    STAGE_A(1, 1); STAGE_B(1, 1);
    STAGE_A(2, 2); STAGE_B(2, 2);

    K_ITER(0, 8)
    K_ITER(1, 8)
    K_ITER(2, 8)
    K_ITER(3, 8)
    K_ITER(4, 8)
    K_ITER(5, 8)
    K_ITER(6, 4)
    K_ITER(7, 0)

    // epilogue: per-row argmin. C layout: col=l&15 (W idx), row=(l>>4)*4+r (X row).
    unsigned long long* mlds = (unsigned long long*)lds;  // [256][4]; slot0 quiesced
    float hw[4];
#pragma unroll
    for (int nj = 0; nj < 4; nj++)
        hw[nj] = hwsq[nbase + wn * 64 + nj * 16 + (l & 15)];

#pragma unroll
    for (int mi = 0; mi < 8; mi++) {
#pragma unroll
        for (int r = 0; r < 4; r++) {
            float bv = 3.4e38f; int bi = 0;
#pragma unroll
            for (int nj = 0; nj < 4; nj++) {
                const float v = hw[nj] - acc[mi][nj][r];
                const int idx = nbase + wn * 64 + nj * 16 + (l & 15);
                if (v < bv) { bv = v; bi = idx; }
            }
            unsigned long long pk =
                ((unsigned long long)__float_as_uint(bv + 1.0f) << 32) | (unsigned)bi;
#pragma unroll
            for (int off = 1; off < 16; off <<= 1) {
                const unsigned long long o = __shfl_xor(pk, off);
                if (o < pk) pk = o;
            }
            if ((l & 15) == 0)
                mlds[(wm * 128 + mi * 16 + (l >> 4) * 4 + r) * 4 + wn] = pk;
        }
    }
    __syncthreads();
    if (t < BM) {
        unsigned long long p = mlds[t * 4];
#pragma unroll
        for (int q = 1; q < 4; q++) {
            const unsigned long long o = mlds[t * 4 + q];
            if (o < p) p = o;
        }
        atomicMin(&packs[m0 + t], p);
    }
}

// ---------------- merge: gather W row, loss from proxy, counts ----------------
__global__ __launch_bounds__(256) void merge_kernel(const float* __restrict__ W,
                                                    const unsigned long long* __restrict__ packs,
                                                    const float* __restrict__ xsq,
                                                    int* __restrict__ counts,
                                                    float* __restrict__ loss_slots,
                                                    float* __restrict__ outq)
{
    const int l  = threadIdx.x & 63;
    const int wv = threadIdx.x >> 6;
    const int n  = blockIdx.x * 4 + wv;

    const unsigned long long p = packs[n];
    const int   idx = (int)(unsigned)(p & 0xffffffffull);
    const float bv  = __uint_as_float((unsigned)(p >> 32)) - 1.0f;  // min proxy

    const float4 w4 = ((const float4*)(W + (size_t)idx * D_DIM))[l];
    float* orow = outq + (size_t)n * D_DIM + l * 4;  // outq 4B-aligned only
    orow[0] = w4.x; orow[1] = w4.y; orow[2] = w4.z; orow[3] = w4.w;

    if (l == 0) {
        atomicAdd(&counts[idx], 1);
        // ||x-w||^2 = xsq + 2*(0.5||w||^2 - x.w)
        atomicAdd(&loss_slots[blockIdx.x & 63], xsq[n] + 2.0f * bv);
    }
}

// ---------------- finalize ----------------
__global__ __launch_bounds__(256) void finalize_kernel(const int* __restrict__ counts,
                                                       const float* __restrict__ loss_slots,
                                                       float* __restrict__ out)
{
    const int tid = threadIdx.x;
    float ent = 0.f;
    for (int k = tid; k < K_EMB; k += 256) {
        const float p = (float)counts[k] * (1.0f / (float)M_IN);
        ent += p * logf(p + 1e-10f);
    }
#pragma unroll
    for (int off = 32; off; off >>= 1) ent += __shfl_xor(ent, off);
    __shared__ float red[4];
    if ((tid & 63) == 0) red[tid >> 6] = ent;
    __syncthreads();
    if (tid == 0) {
        const float e = red[0] + red[1] + red[2] + red[3];
        float ls = 0.f;
        for (int i = 0; i < 64; i++) ls += loss_slots[i];
        out[0] = 1.25f * ls / ((float)M_IN * (float)D_DIM);
        out[1 + (size_t)M_IN * D_DIM] = expf(-e);
    }
}

extern "C" void kernel_launch(void* const* d_in, const int* in_sizes, int n_in,
                              void* d_out, int out_size, void* d_ws, size_t ws_size,
                              hipStream_t stream)
{
    const float* X = (const float*)d_in[0];
    const float* W = (const float*)d_in[1];
    float* out = (float*)d_out;
    char*  ws  = (char*)d_ws;

    float* hwsq               = (float*)(ws + WS_HWSQ);
    unsigned long long* packs = (unsigned long long*)(ws + WS_PACKS);
    int*   counts             = (int*)(ws + WS_COUNTS);
    float* loss_slots         = (float*)(ws + WS_LOSS);
    float* xsq                = (float*)(ws + WS_XSQ);

    // bf16 staging inside d_out's quantized region (overwritten by merge afterwards)
    unsigned short* Xb = (unsigned short*)((char*)d_out + 16);
    unsigned short* Wb = (unsigned short*)((char*)d_out + 16 + 16777216);

    convx_kernel<<<M_IN / 4, 256, 0, stream>>>(X, Xb, xsq, packs);
    convw_kernel<<<K_EMB / 4, 256, 0, stream>>>(W, Wb, hwsq, counts, loss_slots);
    dist_kernel<<<(M_IN / BM) * (K_EMB / BN), 512, 0, stream>>>(Xb, Wb, hwsq, packs);
    merge_kernel<<<M_IN / 4, 256, 0, stream>>>(W, packs, xsq, counts, loss_slots, out + 1);
    finalize_kernel<<<1, 256, 0, stream>>>(counts, loss_slots, out);
}

// Round 5
// 244.284 us; speedup vs baseline: 1.7636x; 1.7636x over previous
//
#include <hip/hip_runtime.h>
#include <hip/hip_bf16.h>

#define M_IN  32768
#define K_EMB 4096
#define D_DIM 256

#define BM 256
#define BN 256
#define BK 32     // K-tile: [256 rows][32 bf16 = 64B]; reads are at the ds_read_b128 bank floor

// ---- ws layout (bytes) ----
#define WS_HWSQ   0         // float[4096]
#define WS_PACKS  16384     // u64[32768]
#define WS_COUNTS 278528    // int[4096]
#define WS_LOSS   294912    // float[64]
#define WS_XSQ    295168    // float[32768]

using f32x4  = __attribute__((ext_vector_type(4))) float;
using bf16x8 = __attribute__((ext_vector_type(8))) short;

#define GLL16(g, p) __builtin_amdgcn_global_load_lds( \
    (const __attribute__((address_space(1))) void*)(g), \
    (__attribute__((address_space(3))) void*)(p), 16, 0, 0)

__device__ __forceinline__ unsigned short bf16_rtn(float f) {
    __hip_bfloat16 h = __float2bfloat16(f);
    return *reinterpret_cast<unsigned short*>(&h);
}

// ---------------- convx: X -> bf16, xsq per row, packs init ----------------
__global__ __launch_bounds__(256) void convx_kernel(const float* __restrict__ X,
                                                    unsigned short* __restrict__ Xb,
                                                    float* __restrict__ xsq,
                                                    unsigned long long* __restrict__ packs)
{
    const int l  = threadIdx.x & 63;
    const int wv = threadIdx.x >> 6;
    const int n  = blockIdx.x * 4 + wv;
    float4 v = ((const float4*)(X + (size_t)n * D_DIM))[l];
    float s = v.x * v.x + v.y * v.y + v.z * v.z + v.w * v.w;
    union { unsigned short u[4]; uint2 q; } p;
    p.u[0] = bf16_rtn(v.x); p.u[1] = bf16_rtn(v.y);
    p.u[2] = bf16_rtn(v.z); p.u[3] = bf16_rtn(v.w);
    ((uint2*)(Xb + (size_t)n * D_DIM))[l] = p.q;
#pragma unroll
    for (int off = 32; off; off >>= 1) s += __shfl_xor(s, off);
    if (l == 0) { xsq[n] = s; packs[n] = ~0ull; }
}

// ---------------- convw: W -> bf16 + 0.5||w||^2 + zero counts/loss ----------------
__global__ __launch_bounds__(256) void convw_kernel(const float* __restrict__ W,
                                                    unsigned short* __restrict__ Wb,
                                                    float* __restrict__ hwsq,
                                                    int* __restrict__ counts,
                                                    float* __restrict__ loss_slots)
{
    const int l = threadIdx.x & 63;
    const int k = blockIdx.x * 4 + (threadIdx.x >> 6);
    const int g = blockIdx.x * 256 + threadIdx.x;
    if (g < K_EMB) counts[g] = 0;
    if (g < 64)    loss_slots[g] = 0.f;
    float4 v = ((const float4*)(W + (size_t)k * D_DIM))[l];
    float s = v.x * v.x + v.y * v.y + v.z * v.z + v.w * v.w;
    union { unsigned short u[4]; uint2 q; } p;
    p.u[0] = bf16_rtn(v.x); p.u[1] = bf16_rtn(v.y);
    p.u[2] = bf16_rtn(v.z); p.u[3] = bf16_rtn(v.w);
    ((uint2*)(Wb + (size_t)k * D_DIM))[l] = p.q;
#pragma unroll
    for (int off = 32; off; off >>= 1) s += __shfl_xor(s, off);
    if (l == 0) hwsq[k] = 0.5f * s;
}

// ---------------- dist: 256x256, BK=32, 4-slot counted-vmcnt, XOR-swizzled LDS ----------------
// Swizzle (verified involution): LDS[row][c] holds data[row][c ^ (((row%16)>>1)&3)].
// Stage: linear LDS dest (lane*16); pre-swizzled global source chunk (l&3)^((l>>3)&3).
// Read: col byte = ((l>>4)*16) ^ ((((l&15)>>1)&3)<<4)  -> retrieves data chunk l>>4.

#define STAGE_A(KT, S) { \
  _Pragma("unroll") \
  for (int j_ = 0; j_ < 2; ++j_) { \
    const int row_ = (j_*8 + w)*16 + (l >> 2); \
    const int ch_  = ((l & 3) ^ ((l >> 3) & 3)); \
    const unsigned short* src_ = Xb + (size_t)(m0 + row_) * D_DIM + (KT)*BK + ch_*8; \
    GLL16(src_, lds + (S)*32768 + (j_*8 + w)*1024); \
  } }

#define STAGE_B(KT, S) { \
  _Pragma("unroll") \
  for (int j_ = 0; j_ < 2; ++j_) { \
    const int row_ = (j_*8 + w)*16 + (l >> 2); \
    const int ch_  = ((l & 3) ^ ((l >> 3) & 3)); \
    const unsigned short* src_ = Wb + (size_t)(nbase + row_) * D_DIM + (KT)*BK + ch_*8; \
    GLL16(src_, lds + (S)*32768 + 16384 + (j_*8 + w)*1024); \
  } }

#define K_ITER(T, VM)                                                          \
  {                                                                            \
    asm volatile("s_waitcnt vmcnt(" #VM ")" ::: "memory");                     \
    __builtin_amdgcn_s_barrier();                                              \
    __builtin_amdgcn_sched_barrier(0);                                         \
    const char* As_ = (const char*)lds + ((T)&3)*32768;                        \
    const char* Bs_ = As_ + 16384;                                             \
    if ((T) < 5) STAGE_A((T)+3, ((T)+3)&3);                                    \
    bf16x8 bfr[4], af[4];                                                      \
    _Pragma("unroll")                                                          \
    for (int nj = 0; nj < 4; nj++)                                             \
      bfr[nj] = *(const bf16x8*)(Bs_ + (rbB + nj*16)*64 + cswz);               \
    _Pragma("unroll")                                                          \
    for (int mi = 0; mi < 4; mi++)                                             \
      af[mi] = *(const bf16x8*)(As_ + (rbA + mi*16)*64 + cswz);                \
    asm volatile("s_waitcnt lgkmcnt(0)" ::: "memory");                         \
    __builtin_amdgcn_sched_barrier(0);                                         \
    __builtin_amdgcn_s_setprio(1);                                             \
    _Pragma("unroll")                                                          \
    for (int mi = 0; mi < 4; mi++)                                             \
      _Pragma("unroll")                                                        \
      for (int nj = 0; nj < 4; nj++)                                           \
        acc[mi][nj] = __builtin_amdgcn_mfma_f32_16x16x32_bf16(                 \
            af[mi], bfr[nj], acc[mi][nj], 0, 0, 0);                            \
    __builtin_amdgcn_s_setprio(0);                                             \
    if ((T) < 5) STAGE_B((T)+3, ((T)+3)&3);                                    \
    _Pragma("unroll")                                                          \
    for (int mi = 0; mi < 4; mi++)                                             \
      af[mi] = *(const bf16x8*)(As_ + (rbA + 64 + mi*16)*64 + cswz);           \
    asm volatile("s_waitcnt lgkmcnt(0)" ::: "memory");                         \
    __builtin_amdgcn_sched_barrier(0);                                         \
    __builtin_amdgcn_s_setprio(1);                                             \
    _Pragma("unroll")                                                          \
    for (int mi = 0; mi < 4; mi++)                                             \
      _Pragma("unroll")                                                        \
      for (int nj = 0; nj < 4; nj++)                                           \
        acc[4+mi][nj] = __builtin_amdgcn_mfma_f32_16x16x32_bf16(               \
            af[mi], bfr[nj], acc[4+mi][nj], 0, 0, 0);                          \
    __builtin_amdgcn_s_setprio(0);                                             \
  }

__global__ __launch_bounds__(512, 2) void dist_kernel(const unsigned short* __restrict__ Xb,
                                                      const unsigned short* __restrict__ Wb,
                                                      const float* __restrict__ hwsq,
                                                      unsigned long long* __restrict__ packs)
{
    __shared__ char lds[131072];   // 4 slots x (A 16KB + B 16KB)

    const int t = threadIdx.x;
    const int l = t & 63;
    const int w = t >> 6;
    const int wm = w >> 2, wn = w & 3;

    const int id  = blockIdx.x;                      // 2048 blocks, 2048%8==0 -> bijective
    const int swz = (id & 7) * 256 + (id >> 3);
    const int nb = swz & 15, mb = swz >> 4;
    const int m0 = mb * BM, nbase = nb * BN;

    const int rbA = wm * 128 + (l & 15);
    const int rbB = wn * 64  + (l & 15);
    const int cswz = ((l >> 4) * 16) ^ (((((l & 15)) >> 1) & 3) << 4);  // swizzled col byte

    f32x4 acc[8][4];
#pragma unroll
    for (int mi = 0; mi < 8; mi++)
#pragma unroll
        for (int nj = 0; nj < 4; nj++) acc[mi][nj] = (f32x4){0.f, 0.f, 0.f, 0.f};

    STAGE_A(0, 0); STAGE_B(0, 0);
    STAGE_A(1, 1); STAGE_B(1, 1);
    STAGE_A(2, 2); STAGE_B(2, 2);

    K_ITER(0, 8)
    K_ITER(1, 8)
    K_ITER(2, 8)
    K_ITER(3, 8)
    K_ITER(4, 8)
    K_ITER(5, 8)
    K_ITER(6, 4)
    K_ITER(7, 0)

    // epilogue: per-row argmin. C layout: col=l&15 (W idx), row=(l>>4)*4+r.
    unsigned long long* mlds = (unsigned long long*)lds;  // slot 0 quiesced since iter 4
    float hw[4];
#pragma unroll
    for (int nj = 0; nj < 4; nj++)
        hw[nj] = hwsq[nbase + wn * 64 + nj * 16 + (l & 15)];

#pragma unroll
    for (int mi = 0; mi < 8; mi++) {
#pragma unroll
        for (int r = 0; r < 4; r++) {
            float bv = 3.4e38f; int bi = 0;
#pragma unroll
            for (int nj = 0; nj < 4; nj++) {
                const float v = hw[nj] - acc[mi][nj][r];
                const int idx = nbase + wn * 64 + nj * 16 + (l & 15);
                if (v < bv) { bv = v; bi = idx; }
            }
            unsigned long long pk =
                ((unsigned long long)__float_as_uint(bv + 1.0f) << 32) | (unsigned)bi;
#pragma unroll
            for (int off = 1; off < 16; off <<= 1) {
                const unsigned long long o = __shfl_xor(pk, off);
                if (o < pk) pk = o;
            }
            if ((l & 15) == 0)
                mlds[(wm * 128 + mi * 16 + (l >> 4) * 4 + r) * 4 + wn] = pk;
        }
    }
    __syncthreads();
    if (t < BM) {
        unsigned long long p = mlds[t * 4];
#pragma unroll
        for (int q = 1; q < 4; q++) {
            const unsigned long long o = mlds[t * 4 + q];
            if (o < p) p = o;
        }
        atomicMin(&packs[m0 + t], p);
    }
}

// ---------------- merge: 64 rows/block, 16 rows/wave, shifted float4 stores ----------------
__global__ __launch_bounds__(256) void merge_kernel(const float* __restrict__ W,
                                                    const unsigned long long* __restrict__ packs,
                                                    const float* __restrict__ xsq,
                                                    int* __restrict__ counts,
                                                    float* __restrict__ loss_slots,
                                                    char* __restrict__ outbase /* = (char*)d_out+4 */)
{
    const int l   = threadIdx.x & 63;
    const int wv  = threadIdx.x >> 6;
    const int n0w = blockIdx.x * 64 + wv * 16;   // this wave's 16 rows

    // one coalesced pack load per lane (lanes 16-63 duplicate lanes 0-15)
    const unsigned long long pk = packs[n0w + (l & 15)];
    const int pkl = (int)(unsigned)(pk & 0xffffffffull);

    // counts: 16 active lanes, one masked atomic instr per wave
    if (l < 16) atomicAdd(&counts[pkl], 1);

    // loss: all 64 lanes hold valid (4x-duplicated) data -> full reduce * 0.25
    float ls = xsq[n0w + (l & 15)] + 2.0f * (__uint_as_float((unsigned)(pk >> 32)) - 1.0f);
#pragma unroll
    for (int off = 32; off; off >>= 1) ls += __shfl_xor(ls, off);
    if (l == 0) atomicAdd(&loss_slots[(blockIdx.x * 4 + wv) & 63], 0.25f * ls);

    // gather: 16 independent float4 loads (ILP), lane l covers elements 4l..4l+3
    float4 v[16];
#pragma unroll
    for (int r = 0; r < 16; r++) {
        const int idxr = __shfl(pkl, r);
        v[r] = ((const float4*)(W + (size_t)idxr * D_DIM))[l];
    }

    // stores: out row base byte = outbase + n*1024 (outbase is d_out+4, so +12+16l is 16B-aligned)
#pragma unroll
    for (int r = 0; r < 16; r++) {
        char* bp = outbase + (size_t)(n0w + r) * 1024;
        const float nx = __shfl_down(v[r].x, 1);
        const float ny = __shfl_down(v[r].y, 1);
        const float nz = __shfl_down(v[r].z, 1);
        if (l < 63)
            *(float4*)(bp + 12 + 16 * l) = make_float4(v[r].w, nx, ny, nz);  // elems 4l+3..4l+6
        if (l == 0) {
            ((float*)bp)[0] = v[r].x; ((float*)bp)[1] = v[r].y; ((float*)bp)[2] = v[r].z;
        }
        if (l == 63) ((float*)bp)[255] = v[r].w;
    }
}

// ---------------- finalize ----------------
__global__ __launch_bounds__(256) void finalize_kernel(const int* __restrict__ counts,
                                                       const float* __restrict__ loss_slots,
                                                       float* __restrict__ out)
{
    const int tid = threadIdx.x;
    float ent = 0.f;
    for (int k = tid; k < K_EMB; k += 256) {
        const float p = (float)counts[k] * (1.0f / (float)M_IN);
        ent += p * logf(p + 1e-10f);
    }
#pragma unroll
    for (int off = 32; off; off >>= 1) ent += __shfl_xor(ent, off);
    __shared__ float red[4];
    if ((tid & 63) == 0) red[tid >> 6] = ent;
    __syncthreads();
    if (tid == 0) {
        const float e = red[0] + red[1] + red[2] + red[3];
        float ls = 0.f;
        for (int i = 0; i < 64; i++) ls += loss_slots[i];
        out[0] = 1.25f * ls / ((float)M_IN * (float)D_DIM);
        out[1 + (size_t)M_IN * D_DIM] = expf(-e);
    }
}

extern "C" void kernel_launch(void* const* d_in, const int* in_sizes, int n_in,
                              void* d_out, int out_size, void* d_ws, size_t ws_size,
                              hipStream_t stream)
{
    const float* X = (const float*)d_in[0];
    const float* W = (const float*)d_in[1];
    float* out = (float*)d_out;
    char*  ws  = (char*)d_ws;

    float* hwsq               = (float*)(ws + WS_HWSQ);
    unsigned long long* packs = (unsigned long long*)(ws + WS_PACKS);
    int*   counts             = (int*)(ws + WS_COUNTS);
    float* loss_slots         = (float*)(ws + WS_LOSS);
    float* xsq                = (float*)(ws + WS_XSQ);

    // bf16 staging inside d_out's quantized region (consumed by dist, overwritten by merge)
    unsigned short* Xb = (unsigned short*)((char*)d_out + 16);
    unsigned short* Wb = (unsigned short*)((char*)d_out + 16 + 16777216);

    convx_kernel<<<M_IN / 4, 256, 0, stream>>>(X, Xb, xsq, packs);
    convw_kernel<<<K_EMB / 4, 256, 0, stream>>>(W, Wb, hwsq, counts, loss_slots);
    dist_kernel<<<(M_IN / BM) * (K_EMB / BN), 512, 0, stream>>>(Xb, Wb, hwsq, packs);
    merge_kernel<<<M_IN / 64, 256, 0, stream>>>(W, packs, xsq, counts, loss_slots,
                                                (char*)d_out + 4);
    finalize_kernel<<<1, 256, 0, stream>>>(counts, loss_slots, out);
}